// Round 7
// baseline (163.582 us; speedup 1.0000x reference)
//
#include <hip/hip_runtime.h>
#include <hip/hip_bf16.h>

// Shapes (fixed): B=4, T=64, L=128, D=768, H=12, d=64
#define NB 4
#define NT 64
#define NL 128
#define ND 768
#define NH 12
#define HD 64

typedef __attribute__((ext_vector_type(8))) short short8;
typedef __attribute__((ext_vector_type(4))) float f32x4;

typedef __attribute__((address_space(3))) unsigned int lds_u32;
typedef __attribute__((address_space(1))) const unsigned int glob_u32;

static __device__ __forceinline__ unsigned short f2b(float x) {
    __hip_bfloat16 h = __float2bfloat16(x);   // RNE
    return *reinterpret_cast<unsigned short*>(&h);
}
// async global->LDS, 16B/lane; LDS dest = base + lane*16 (wave-uniform base)
static __device__ __forceinline__ void gl2lds16(const void* g, void* l) {
    __builtin_amdgcn_global_load_lds((glob_u32*)g, (lds_u32*)l, 16, 0, 0);
}

// conversion chunk boundaries (8-float chunks): Wq | edu | Wk | Wv
#define WQ_C   73728u
#define EDU_C  98304u
#define WK_C   172032u
#define NCHUNK 245760u

// ---------------------------------------------------------------------------
// Kernel 1: streaming fp32 -> bf16 of Wq, edu, Wk, Wv (~13 MB traffic).
// te is NOT converted — fused_qm reg-stages fp32 te directly.
// ---------------------------------------------------------------------------
__global__ __launch_bounds__(256) void conv_bf16(
    const float* __restrict__ Wq, const float* __restrict__ edu,
    const float* __restrict__ Wk, const float* __restrict__ Wv,
    unsigned short* __restrict__ dst)
{
    size_t c = (size_t)blockIdx.x * 256 + threadIdx.x;
    if (c >= NCHUNK) return;
    const float* s;
    if (c < WQ_C)       s = Wq  + c * 8;
    else if (c < EDU_C) s = edu + (c - WQ_C)  * 8;
    else if (c < WK_C)  s = Wk  + (c - EDU_C) * 8;
    else                s = Wv  + (c - WK_C)  * 8;
    float4 x = *(const float4*)s;
    float4 y = *(const float4*)(s + 4);
    unsigned short v[8];
    v[0] = f2b(x.x); v[1] = f2b(x.y); v[2] = f2b(x.z); v[3] = f2b(x.w);
    v[4] = f2b(y.x); v[5] = f2b(y.y); v[6] = f2b(y.z); v[7] = f2b(y.w);
    *(short8*)(dst + c * 8) = *(short8*)v;
}

// ---------------------------------------------------------------------------
// Kernel 2: fused K/V projection (bf16 MFMA) + speaker-bucket prefix scan.
// (unchanged — verified rounds 4/5/6)
// ---------------------------------------------------------------------------
__global__ __launch_bounds__(256) void kvm(
    const unsigned short* __restrict__ edu_b,
    const unsigned short* __restrict__ wk_b,
    const unsigned short* __restrict__ wv_b,
    const int* __restrict__ spk,
    unsigned short* __restrict__ Mt)
{
    const int h = blockIdx.x, b = blockIdx.y, eh = blockIdx.z;

    __shared__ float bucket[8][32][65];
    __shared__ float k_s[64][68];
    __shared__ float v_s[64][36];
    __shared__ __align__(16) unsigned short stage[10240];
    __shared__ int spk_s[64];
    unsigned short* edu_s = stage;
    unsigned short* wk_s  = stage + 4096;
    unsigned short* wv_s  = stage + 8192;

    const int tid = threadIdx.x, lane = tid & 63, wvx = tid >> 6;
    const int lr = lane & 15, lg = lane >> 4, r8 = lane >> 3, l8 = lane & 7;

    { float* p = &bucket[0][0][0];
      for (int i = tid; i < 8 * 32 * 65; i += 256) p[i] = 0.f; }
    if (tid < 64) spk_s[tid] = spk[b * NT + tid];

    const unsigned short* edub = edu_b + (size_t)(b * 64) * ND;
    const unsigned short* wkb  = wk_b + (size_t)(h * 64) * ND;
    const unsigned short* wvb  = wv_b + (size_t)(h * 64 + eh * 32) * ND;

    f32x4 acc_k[4], acc_v[2];
    #pragma unroll
    for (int i = 0; i < 4; i++) acc_k[i] = (f32x4){0.f, 0.f, 0.f, 0.f};
    #pragma unroll
    for (int i = 0; i < 2; i++) acc_v[i] = (f32x4){0.f, 0.f, 0.f, 0.f};

    const int sswz = ((l8 ^ r8) * 8);

    for (int k0 = 0; k0 < ND; k0 += 64) {
        __syncthreads();
        #pragma unroll
        for (int j = 0; j < 5; j++) {
            const int cid = wvx * 5 + j;
            const unsigned short* gs; unsigned short* ls;
            if (cid < 8)       { gs = edub + (size_t)(cid * 8 + r8) * ND;        ls = edu_s + cid * 512; }
            else if (cid < 16) { gs = wkb  + (size_t)((cid - 8) * 8 + r8) * ND;  ls = wk_s + (cid - 8) * 512; }
            else               { gs = wvb  + (size_t)((cid - 16) * 8 + r8) * ND; ls = wv_s + (cid - 16) * 512; }
            gl2lds16(gs + k0 + sswz, ls);
        }
        __syncthreads();
        #pragma unroll
        for (int k32 = 0; k32 < 2; k32++) {
            const int cx = (((k32 * 4 + lg) ^ (lr & 7)) * 8);
            short8 eb = *(const short8*)&edu_s[(wvx * 16 + lr) * 64 + cx];
            #pragma unroll
            for (int jb = 0; jb < 4; jb++) {
                short8 ak = *(const short8*)&wk_s[(jb * 16 + lr) * 64 + cx];
                acc_k[jb] = __builtin_amdgcn_mfma_f32_16x16x32_bf16(ak, eb, acc_k[jb], 0, 0, 0);
            }
            #pragma unroll
            for (int jb = 0; jb < 2; jb++) {
                short8 av = *(const short8*)&wv_s[(jb * 16 + lr) * 64 + cx];
                acc_v[jb] = __builtin_amdgcn_mfma_f32_16x16x32_bf16(av, eb, acc_v[jb], 0, 0, 0);
            }
        }
    }

    {
        const int t = wvx * 16 + lr;
        #pragma unroll
        for (int jb = 0; jb < 4; jb++) *(f32x4*)&k_s[t][jb * 16 + lg * 4] = acc_k[jb];
        #pragma unroll
        for (int jb = 0; jb < 2; jb++) *(f32x4*)&v_s[t][jb * 16 + lg * 4] = acc_v[jb];
    }
    __syncthreads();

    const int e = tid & 31, dg = tid >> 5;
    for (int t = 0; t < NT; t++) {
        const int s = spk_s[t];
        const float vv = v_s[t][e];
        unsigned short tmp[8];
        #pragma unroll
        for (int jj = 0; jj < 8; jj++) {
            float m = bucket[s][e][dg * 8 + jj] + k_s[t][dg * 8 + jj] * vv;
            bucket[s][e][dg * 8 + jj] = m;
            tmp[jj] = f2b(m);
        }
        unsigned short* mpp = Mt + (((size_t)(b * NT + t) * NH + h) * HD + eh * 32 + e) * HD + dg * 8;
        *(short8*)mpp = *(short8*)tmp;
    }
}

// ---------------------------------------------------------------------------
// Kernel 3: fused bf16 MFMA  q^T = Wq_hp @ te^T (K=768), a = q @ M, residual.
//  - te: fp32 in HBM, reg-staged (T14): loads for tile k+1 issued right after
//    the barrier, land under COMPUTE(k)'s MFMAs; RNE-convert + ds_write_b128
//    into the swizzled bf16 layout between barriers. Once per element.
//  - wq: bf16, double-buffered global_load_lds (drain hidden under COMPUTE).
//  - Mt: NOT in LDS — GEMM2 B-frags loaded straight from global (L2-hot).
// LDS 48 KB (te 16 + wq 2x16), q_s phase overlays; 3 blocks/CU.
// ---------------------------------------------------------------------------
__global__ __launch_bounds__(256, 3) void fused_qm(
    const float* __restrict__ te,
    const unsigned short* __restrict__ wq_b,
    const unsigned short* __restrict__ Mt,
    float* __restrict__ out)
{
    const int orig = blockIdx.x;
    const int id   = (orig & 7) * 192 + (orig >> 3);   // bijective XCD swizzle
    const int hp   = id % 6;
    const int bt   = id / 6;

    __shared__ __align__(16) unsigned short smem[24576];   // 49152 B
    unsigned short* te_s = smem;            // [128][64] bf16 (swizzled chunks)
    unsigned short* wq0  = smem + 8192;     // [128][64]
    unsigned short* wq1  = smem + 16384;    // [128][64]
    unsigned short* q_s  = smem;            // phase 2: [128][136] = 17408 ush

    const int tid  = threadIdx.x;
    const int lane = tid & 63;
    const int wvx  = tid >> 6;
    const int lr   = lane & 15;
    const int lg   = lane >> 4;
    const int wm   = wvx >> 1;
    const int wn   = wvx & 1;
    const int r8   = lane >> 3;
    const int l8   = lane & 7;
    const int sswz = (l8 ^ r8) * 8;         // wq source pre-swizzle (ush)
    const int srow = tid >> 3;              // 0..31  te staging row-in-pass
    const int sc   = tid & 7;               // te storage chunk

    const float*          teb = te + (size_t)bt * NL * ND;
    const unsigned short* wqb = wq_b + (size_t)hp * 128 * ND;

    f32x4 acc[4][4];
    #pragma unroll
    for (int i = 0; i < 4; i++)
        #pragma unroll
        for (int j = 0; j < 4; j++) acc[i][j] = (f32x4){0.f, 0.f, 0.f, 0.f};

    float4 ld[4][2];   // in-flight te fp32 (32 VGPR)

    // issue next tile's te loads (global->reg); latency hides under COMPUTE
    auto LOADREG = [&](int k0) {
        #pragma unroll
        for (int p = 0; p < 4; p++) {
            const int r    = p * 32 + srow;
            const int clog = sc ^ (srow & 7);
            const float* g = teb + (size_t)r * ND + k0 + clog * 8;
            ld[p][0] = *(const float4*)g;
            ld[p][1] = *(const float4*)(g + 4);
        }
    };
    // convert + write staged te to LDS (element (r, clog) at chunk sc = clog^ (r&7))
    auto CVTWRITE = [&]() {
        #pragma unroll
        for (int p = 0; p < 4; p++) {
            const int r = p * 32 + srow;
            unsigned short v[8];
            v[0] = f2b(ld[p][0].x); v[1] = f2b(ld[p][0].y);
            v[2] = f2b(ld[p][0].z); v[3] = f2b(ld[p][0].w);
            v[4] = f2b(ld[p][1].x); v[5] = f2b(ld[p][1].y);
            v[6] = f2b(ld[p][1].z); v[7] = f2b(ld[p][1].w);
            *(short8*)&te_s[r * 64 + sc * 8] = *(short8*)v;
        }
    };
    auto WQSTAGE = [&](unsigned short* buf, int k0) {
        #pragma unroll
        for (int j = 0; j < 4; j++) {
            const int rbase = wvx * 32 + j * 8;
            gl2lds16(wqb + (size_t)(rbase + r8) * ND + k0 + sswz, buf + rbase * 64);
        }
    };
    auto COMPUTE = [&](const unsigned short* wqs) {
        #pragma unroll
        for (int k32 = 0; k32 < 2; k32++) {
            const int cx = (((k32 * 4 + lg) ^ (lr & 7)) * 8);
            short8 af[4], bf[4];
            #pragma unroll
            for (int tm = 0; tm < 4; tm++)
                af[tm] = *(const short8*)&wqs[(wm * 64 + tm * 16 + lr) * 64 + cx];
            #pragma unroll
            for (int tn = 0; tn < 4; tn++)
                bf[tn] = *(const short8*)&te_s[(wn * 64 + tn * 16 + lr) * 64 + cx];
            __builtin_amdgcn_s_setprio(1);
            #pragma unroll
            for (int tm = 0; tm < 4; tm++)
                #pragma unroll
                for (int tn = 0; tn < 4; tn++)
                    acc[tm][tn] = __builtin_amdgcn_mfma_f32_16x16x32_bf16(
                        af[tm], bf[tn], acc[tm][tn], 0, 0, 0);
            __builtin_amdgcn_s_setprio(0);
        }
    };

    // ---- prologue: tile 0 ----
    LOADREG(0);
    WQSTAGE(wq0, 0);
    CVTWRITE();                 // implicit vmcnt wait on ld regs
    __syncthreads();            // wq0 drained + te writes visible

    // ---- K-loop: 12 tiles, wq ping-pong; 2 barriers/tile ----
    for (int k0 = 0; k0 < ND; k0 += 128) {
        // tile A (k0): compute from wq0/te_s; prefetch tile A+1
        LOADREG(k0 + 64);                       // k0+64 <= 704, always valid
        WQSTAGE(wq1, k0 + 64);
        COMPUTE(wq0);
        __syncthreads();        // drains A+1 loads (landed under COMPUTE); reads done
        CVTWRITE();
        __syncthreads();        // te(A+1) visible
        // tile B (k0+64): compute from wq1; prefetch tile B+1
        if (k0 + 128 < ND) { LOADREG(k0 + 128); WQSTAGE(wq0, k0 + 128); }
        COMPUTE(wq1);
        __syncthreads();
        if (k0 + 128 < ND) { CVTWRITE(); }
        __syncthreads();
    }

    // ---- q^T C-frags -> row-major bf16 q_s[l][d] (8B packed writes) ----
    #pragma unroll
    for (int tm = 0; tm < 4; tm++) {
        const int d0 = wm * 64 + tm * 16 + lg * 4;
        #pragma unroll
        for (int tn = 0; tn < 4; tn++) {
            const int ltok = wn * 64 + tn * 16 + lr;
            f32x4 a = acc[tm][tn];
            uint2 w2;
            w2.x = (unsigned)f2b(a.x) | ((unsigned)f2b(a.y) << 16);
            w2.y = (unsigned)f2b(a.z) | ((unsigned)f2b(a.w) << 16);
            *(uint2*)&q_s[ltok * 136 + d0] = w2;
        }
    }

    // ---- issue GEMM2 B-frags from global Mt (L2-hot) before the barrier ----
    const int h2 = wvx & 1;
    const int lh = wvx >> 1;
    const unsigned short* mp = Mt + ((size_t)(bt * NH) + hp * 2 + h2) * (HD * HD);
    short8 bfr[8];
    #pragma unroll
    for (int tn = 0; tn < 4; tn++)
        #pragma unroll
        for (int k32 = 0; k32 < 2; k32++)
            bfr[tn * 2 + k32] =
                *(const short8*)&mp[(tn * 16 + lr) * 64 + k32 * 32 + lg * 8];
    __syncthreads();            // q_s visible

    // ---- GEMM2: per-wave one (token-half, head), 64x64, K=64 ----
    f32x4 acc2[4][4];
    #pragma unroll
    for (int i = 0; i < 4; i++)
        #pragma unroll
        for (int j = 0; j < 4; j++) acc2[i][j] = (f32x4){0.f, 0.f, 0.f, 0.f};

    #pragma unroll
    for (int k32 = 0; k32 < 2; k32++) {
        const int ko = k32 * 32 + lg * 8;
        short8 af[4];
        #pragma unroll
        for (int tm = 0; tm < 4; tm++)
            af[tm] = *(const short8*)&q_s[(lh * 64 + tm * 16 + lr) * 136 + h2 * 64 + ko];
        #pragma unroll
        for (int tm = 0; tm < 4; tm++)
            #pragma unroll
            for (int tn = 0; tn < 4; tn++)
                acc2[tm][tn] = __builtin_amdgcn_mfma_f32_16x16x32_bf16(
                    af[tm], bfr[tn * 2 + k32], acc2[tm][tn], 0, 0, 0);
    }

    // ---- epilogue: out = fp32 te + a (te L2-hot from staging) ----
    float* ob = out + (size_t)bt * NL * ND;
    #pragma unroll
    for (int tm = 0; tm < 4; tm++) {
        const int l0 = lh * 64 + tm * 16 + lg * 4;
        #pragma unroll
        for (int tn = 0; tn < 4; tn++) {
            const int cg = hp * 128 + h2 * 64 + tn * 16 + lr;
            f32x4 a = acc2[tm][tn];
            #pragma unroll
            for (int r = 0; r < 4; r++) {
                size_t gi = (size_t)(l0 + r) * ND + cg;
                ob[gi] = teb[gi] + a[r];
            }
        }
    }
}

// ---------------------------------------------------------------------------
extern "C" void kernel_launch(void* const* d_in, const int* in_sizes, int n_in,
                              void* d_out, int out_size, void* d_ws, size_t ws_size,
                              hipStream_t stream)
{
    const int*   spk = (const int*)d_in[1];
    const float* te  = (const float*)d_in[2];
    const float* edu = (const float*)d_in[3];
    const float* Wk  = (const float*)d_in[4];
    const float* Wv  = (const float*)d_in[5];
    const float* Wq  = (const float*)d_in[6];
    float* out = (float*)d_out;

    // ws layout (ush units), ~29 MB total:
    unsigned short* bf    = (unsigned short*)d_ws;
    unsigned short* wq_bb = bf;                 //   589824
    unsigned short* edu_b = bf + 589824u;       //   196608
    unsigned short* wk_bb = bf + 786432u;       //   589824
    unsigned short* wv_bb = bf + 1376256u;      //   589824
    unsigned short* Mtbuf = bf + 1966080u;      // 12582912

    conv_bf16<<<960,             256, 0, stream>>>(Wq, edu, Wk, Wv, bf);
    kvm      <<<dim3(NH, NB, 2), 256, 0, stream>>>(edu_b, wk_bb, wv_bb, spk, Mtbuf);
    fused_qm <<<6 * NT * NB,     256, 0, stream>>>(te, wq_bb, Mtbuf, out);
}

// Round 8
// 107.288 us; speedup vs baseline: 1.5247x; 1.5247x over previous
//
#include <hip/hip_runtime.h>
#include <hip/hip_bf16.h>

// Shapes (fixed): B=4, T=64, L=128, D=768, H=12, d=64
#define NB 4
#define NT 64
#define NL 128
#define ND 768
#define NH 12
#define HD 64

typedef __attribute__((ext_vector_type(8))) short short8;
typedef __attribute__((ext_vector_type(4))) float f32x4;

typedef __attribute__((address_space(3))) unsigned int lds_u32;
typedef __attribute__((address_space(1))) const unsigned int glob_u32;

static __device__ __forceinline__ unsigned short f2b(float x) {
    __hip_bfloat16 h = __float2bfloat16(x);   // RNE
    return *reinterpret_cast<unsigned short*>(&h);
}
// async global->LDS, 16B/lane; LDS dest = base + lane*16 (wave-uniform base)
static __device__ __forceinline__ void gl2lds16(const void* g, void* l) {
    __builtin_amdgcn_global_load_lds((glob_u32*)g, (lds_u32*)l, 16, 0, 0);
}

// conversion chunk boundaries (8-float chunks): Wq | edu | Wk | Wv
#define WQ_C   73728u
#define EDU_C  98304u
#define WK_C   172032u
#define NCHUNK 245760u

// ---------------------------------------------------------------------------
// Kernel 1: streaming fp32 -> bf16 of Wq, edu, Wk, Wv (~13 MB traffic, ~2 us).
// te is NOT converted — fused_qm reg-stages + converts fp32 te itself.
// ---------------------------------------------------------------------------
__global__ __launch_bounds__(256) void conv_bf16(
    const float* __restrict__ Wq, const float* __restrict__ edu,
    const float* __restrict__ Wk, const float* __restrict__ Wv,
    unsigned short* __restrict__ dst)
{
    size_t c = (size_t)blockIdx.x * 256 + threadIdx.x;
    if (c >= NCHUNK) return;
    const float* s;
    if (c < WQ_C)       s = Wq  + c * 8;
    else if (c < EDU_C) s = edu + (c - WQ_C)  * 8;
    else if (c < WK_C)  s = Wk  + (c - EDU_C) * 8;
    else                s = Wv  + (c - WK_C)  * 8;
    float4 x = *(const float4*)s;
    float4 y = *(const float4*)(s + 4);
    unsigned short v[8];
    v[0] = f2b(x.x); v[1] = f2b(x.y); v[2] = f2b(x.z); v[3] = f2b(x.w);
    v[4] = f2b(y.x); v[5] = f2b(y.y); v[6] = f2b(y.z); v[7] = f2b(y.w);
    *(short8*)(dst + c * 8) = *(short8*)v;
}

// ---------------------------------------------------------------------------
// Kernel 2: fused K/V projection (bf16 MFMA) + speaker-bucket prefix scan.
// (unchanged — verified rounds 4-7)
// ---------------------------------------------------------------------------
__global__ __launch_bounds__(256) void kvm(
    const unsigned short* __restrict__ edu_b,
    const unsigned short* __restrict__ wk_b,
    const unsigned short* __restrict__ wv_b,
    const int* __restrict__ spk,
    unsigned short* __restrict__ Mt)
{
    const int h = blockIdx.x, b = blockIdx.y, eh = blockIdx.z;

    __shared__ float bucket[8][32][65];
    __shared__ float k_s[64][68];
    __shared__ float v_s[64][36];
    __shared__ __align__(16) unsigned short stage[10240];
    __shared__ int spk_s[64];
    unsigned short* edu_s = stage;
    unsigned short* wk_s  = stage + 4096;
    unsigned short* wv_s  = stage + 8192;

    const int tid = threadIdx.x, lane = tid & 63, wvx = tid >> 6;
    const int lr = lane & 15, lg = lane >> 4, r8 = lane >> 3, l8 = lane & 7;

    { float* p = &bucket[0][0][0];
      for (int i = tid; i < 8 * 32 * 65; i += 256) p[i] = 0.f; }
    if (tid < 64) spk_s[tid] = spk[b * NT + tid];

    const unsigned short* edub = edu_b + (size_t)(b * 64) * ND;
    const unsigned short* wkb  = wk_b + (size_t)(h * 64) * ND;
    const unsigned short* wvb  = wv_b + (size_t)(h * 64 + eh * 32) * ND;

    f32x4 acc_k[4], acc_v[2];
    #pragma unroll
    for (int i = 0; i < 4; i++) acc_k[i] = (f32x4){0.f, 0.f, 0.f, 0.f};
    #pragma unroll
    for (int i = 0; i < 2; i++) acc_v[i] = (f32x4){0.f, 0.f, 0.f, 0.f};

    const int sswz = ((l8 ^ r8) * 8);

    for (int k0 = 0; k0 < ND; k0 += 64) {
        __syncthreads();
        #pragma unroll
        for (int j = 0; j < 5; j++) {
            const int cid = wvx * 5 + j;
            const unsigned short* gs; unsigned short* ls;
            if (cid < 8)       { gs = edub + (size_t)(cid * 8 + r8) * ND;        ls = edu_s + cid * 512; }
            else if (cid < 16) { gs = wkb  + (size_t)((cid - 8) * 8 + r8) * ND;  ls = wk_s + (cid - 8) * 512; }
            else               { gs = wvb  + (size_t)((cid - 16) * 8 + r8) * ND; ls = wv_s + (cid - 16) * 512; }
            gl2lds16(gs + k0 + sswz, ls);
        }
        __syncthreads();
        #pragma unroll
        for (int k32 = 0; k32 < 2; k32++) {
            const int cx = (((k32 * 4 + lg) ^ (lr & 7)) * 8);
            short8 eb = *(const short8*)&edu_s[(wvx * 16 + lr) * 64 + cx];
            #pragma unroll
            for (int jb = 0; jb < 4; jb++) {
                short8 ak = *(const short8*)&wk_s[(jb * 16 + lr) * 64 + cx];
                acc_k[jb] = __builtin_amdgcn_mfma_f32_16x16x32_bf16(ak, eb, acc_k[jb], 0, 0, 0);
            }
            #pragma unroll
            for (int jb = 0; jb < 2; jb++) {
                short8 av = *(const short8*)&wv_s[(jb * 16 + lr) * 64 + cx];
                acc_v[jb] = __builtin_amdgcn_mfma_f32_16x16x32_bf16(av, eb, acc_v[jb], 0, 0, 0);
            }
        }
    }

    {
        const int t = wvx * 16 + lr;
        #pragma unroll
        for (int jb = 0; jb < 4; jb++) *(f32x4*)&k_s[t][jb * 16 + lg * 4] = acc_k[jb];
        #pragma unroll
        for (int jb = 0; jb < 2; jb++) *(f32x4*)&v_s[t][jb * 16 + lg * 4] = acc_v[jb];
    }
    __syncthreads();

    const int e = tid & 31, dg = tid >> 5;
    for (int t = 0; t < NT; t++) {
        const int s = spk_s[t];
        const float vv = v_s[t][e];
        unsigned short tmp[8];
        #pragma unroll
        for (int jj = 0; jj < 8; jj++) {
            float m = bucket[s][e][dg * 8 + jj] + k_s[t][dg * 8 + jj] * vv;
            bucket[s][e][dg * 8 + jj] = m;
            tmp[jj] = f2b(m);
        }
        unsigned short* mpp = Mt + (((size_t)(b * NT + t) * NH + h) * HD + eh * 32 + e) * HD + dg * 8;
        *(short8*)mpp = *(short8*)tmp;
    }
}

// ---------------------------------------------------------------------------
// Kernel 3: fused bf16 MFMA  q^T = Wq_hp @ te^T (K=768), a = q @ M, residual.
// te fp32 in HBM, reg-staged 2-TILES-AHEAD, converted once/element, written
// into a DOUBLE-buffered bf16 te_s -> back to round-6's 1 barrier per k-tile:
//   iter kt: LOADREG(set[kt&1], tile kt+2)   <- lands during this+next phase
//            WQSTAGE(wq[nxt], tile kt+1)     <- gload_lds, drains at barrier
//            CVTWRITE(te[nxt], set[(kt+1)&1])<- regs issued 1 full phase ago
//            COMPUTE(te[cur], wq[cur]); barrier
// Mt: read straight from global in GEMM2 (validated round 7).
// LDS 64 KB (te 2x16 + wq 2x16), q_s overlays; 2 blocks/CU.
// ---------------------------------------------------------------------------
__global__ __launch_bounds__(256, 2) void fused_qm(
    const float* __restrict__ te,
    const unsigned short* __restrict__ wq_b,
    const unsigned short* __restrict__ Mt,
    float* __restrict__ out)
{
    const int orig = blockIdx.x;
    const int id   = (orig & 7) * 192 + (orig >> 3);   // bijective XCD swizzle
    const int hp   = id % 6;
    const int bt   = id / 6;

    __shared__ __align__(16) unsigned short smem[32768];   // 65536 B
    unsigned short* te0 = smem;              // [128][64] bf16, swizzled chunks
    unsigned short* te1 = smem + 8192;
    unsigned short* wq0 = smem + 16384;
    unsigned short* wq1 = smem + 24576;
    unsigned short* q_s = smem;              // phase 2: [128][136] = 17408 ush

    const int tid  = threadIdx.x;
    const int lane = tid & 63;
    const int wvx  = tid >> 6;
    const int lr   = lane & 15;
    const int lg   = lane >> 4;
    const int wm   = wvx >> 1;
    const int wn   = wvx & 1;
    const int r8   = lane >> 3;
    const int l8   = lane & 7;
    const int sswz = (l8 ^ r8) * 8;          // wq source pre-swizzle (ush)
    const int srow = tid >> 3;               // te staging row-in-pass (0..31)
    const int sc   = tid & 7;                // te storage chunk

    const float*          teb = te + (size_t)bt * NL * ND;
    const unsigned short* wqb = wq_b + (size_t)hp * 128 * ND;

    f32x4 acc[4][4];
    #pragma unroll
    for (int i = 0; i < 4; i++)
        #pragma unroll
        for (int j = 0; j < 4; j++) acc[i][j] = (f32x4){0.f, 0.f, 0.f, 0.f};

    float4 ldA[4][2], ldB[4][2];   // two in-flight te fp32 reg sets (tile t in set t&1)

    auto LOADREG = [&](float4 (&dst)[4][2], int k0) {
        #pragma unroll
        for (int p = 0; p < 4; p++) {
            const int r    = p * 32 + srow;
            const int clog = sc ^ (srow & 7);
            const float* g = teb + (size_t)r * ND + k0 + clog * 8;
            dst[p][0] = *(const float4*)g;
            dst[p][1] = *(const float4*)(g + 4);
        }
    };
    auto CVTWRITE = [&](unsigned short* tebuf, const float4 (&src)[4][2]) {
        #pragma unroll
        for (int p = 0; p < 4; p++) {
            const int r = p * 32 + srow;
            unsigned short v[8];
            v[0] = f2b(src[p][0].x); v[1] = f2b(src[p][0].y);
            v[2] = f2b(src[p][0].z); v[3] = f2b(src[p][0].w);
            v[4] = f2b(src[p][1].x); v[5] = f2b(src[p][1].y);
            v[6] = f2b(src[p][1].z); v[7] = f2b(src[p][1].w);
            *(short8*)&tebuf[r * 64 + sc * 8] = *(short8*)v;
        }
    };
    auto WQSTAGE = [&](unsigned short* buf, int k0) {
        #pragma unroll
        for (int j = 0; j < 4; j++) {
            const int rbase = wvx * 32 + j * 8;
            gl2lds16(wqb + (size_t)(rbase + r8) * ND + k0 + sswz, buf + rbase * 64);
        }
    };
    auto COMPUTE = [&](const unsigned short* tes, const unsigned short* wqs) {
        #pragma unroll
        for (int k32 = 0; k32 < 2; k32++) {
            const int cx = (((k32 * 4 + lg) ^ (lr & 7)) * 8);
            short8 af[4], bfv[4];
            #pragma unroll
            for (int tm = 0; tm < 4; tm++)
                af[tm] = *(const short8*)&wqs[(wm * 64 + tm * 16 + lr) * 64 + cx];
            #pragma unroll
            for (int tn = 0; tn < 4; tn++)
                bfv[tn] = *(const short8*)&tes[(wn * 64 + tn * 16 + lr) * 64 + cx];
            #pragma unroll
            for (int tm = 0; tm < 4; tm++)
                #pragma unroll
                for (int tn = 0; tn < 4; tn++)
                    acc[tm][tn] = __builtin_amdgcn_mfma_f32_16x16x32_bf16(
                        af[tm], bfv[tn], acc[tm][tn], 0, 0, 0);
        }
    };

    // ---- prologue: tiles 0 (regs+LDS) and 1 (regs only) ----
    LOADREG(ldA, 0);
    LOADREG(ldB, 64);
    WQSTAGE(wq0, 0);
    CVTWRITE(te0, ldA);          // waits on ldA only (ldB stays in flight)
    __syncthreads();             // te0 visible, wq0 drained

    // ---- K-loop: 12 tiles, unrolled x2 (static buffers/reg-sets) ----
    for (int kt = 0; kt < 12; kt += 2) {
        // even tile kt: cur = te0/wq0, sets: cur=ldA(tile kt), nxt=ldB(tile kt+1)
        if (kt + 2 < 12) LOADREG(ldA, (kt + 2) * 64);
        WQSTAGE(wq1, (kt + 1) * 64);
        CVTWRITE(te1, ldB);
        COMPUTE(te0, wq0);
        __syncthreads();
        // odd tile kt+1: cur = te1/wq1
        if (kt + 3 < 12) LOADREG(ldB, (kt + 3) * 64);
        if (kt + 2 < 12) { WQSTAGE(wq0, (kt + 2) * 64); CVTWRITE(te0, ldA); }
        COMPUTE(te1, wq1);
        __syncthreads();
    }

    // ---- q^T C-frags -> row-major bf16 q_s[l][d] (8B packed writes) ----
    #pragma unroll
    for (int tm = 0; tm < 4; tm++) {
        const int d0 = wm * 64 + tm * 16 + lg * 4;
        #pragma unroll
        for (int tn = 0; tn < 4; tn++) {
            const int ltok = wn * 64 + tn * 16 + lr;
            f32x4 a = acc[tm][tn];
            uint2 w2;
            w2.x = (unsigned)f2b(a.x) | ((unsigned)f2b(a.y) << 16);
            w2.y = (unsigned)f2b(a.z) | ((unsigned)f2b(a.w) << 16);
            *(uint2*)&q_s[ltok * 136 + d0] = w2;
        }
    }

    // ---- GEMM2 B-frags straight from global Mt (L2-hot); issue pre-barrier ----
    const int h2 = wvx & 1;
    const int lh = wvx >> 1;
    const unsigned short* mp = Mt + ((size_t)(bt * NH) + hp * 2 + h2) * (HD * HD);
    short8 bfr[8];
    #pragma unroll
    for (int tn = 0; tn < 4; tn++)
        #pragma unroll
        for (int k32 = 0; k32 < 2; k32++)
            bfr[tn * 2 + k32] =
                *(const short8*)&mp[(tn * 16 + lr) * 64 + k32 * 32 + lg * 8];
    __syncthreads();            // q_s visible

    // ---- GEMM2: per-wave one (token-half, head), 64x64, K=64 ----
    f32x4 acc2[4][4];
    #pragma unroll
    for (int i = 0; i < 4; i++)
        #pragma unroll
        for (int j = 0; j < 4; j++) acc2[i][j] = (f32x4){0.f, 0.f, 0.f, 0.f};

    #pragma unroll
    for (int k32 = 0; k32 < 2; k32++) {
        const int ko = k32 * 32 + lg * 8;
        short8 af[4];
        #pragma unroll
        for (int tm = 0; tm < 4; tm++)
            af[tm] = *(const short8*)&q_s[(lh * 64 + tm * 16 + lr) * 136 + h2 * 64 + ko];
        #pragma unroll
        for (int tm = 0; tm < 4; tm++)
            #pragma unroll
            for (int tn = 0; tn < 4; tn++)
                acc2[tm][tn] = __builtin_amdgcn_mfma_f32_16x16x32_bf16(
                    af[tm], bfr[tn * 2 + k32], acc2[tm][tn], 0, 0, 0);
    }

    // ---- epilogue: out = fp32 te + a (te L2-hot from staging) ----
    float* ob = out + (size_t)bt * NL * ND;
    #pragma unroll
    for (int tm = 0; tm < 4; tm++) {
        const int l0 = lh * 64 + tm * 16 + lg * 4;
        #pragma unroll
        for (int tn = 0; tn < 4; tn++) {
            const int cg = hp * 128 + h2 * 64 + tn * 16 + lr;
            f32x4 a = acc2[tm][tn];
            #pragma unroll
            for (int r = 0; r < 4; r++) {
                size_t gi = (size_t)(l0 + r) * ND + cg;
                ob[gi] = teb[gi] + a[r];
            }
        }
    }
}

// ---------------------------------------------------------------------------
extern "C" void kernel_launch(void* const* d_in, const int* in_sizes, int n_in,
                              void* d_out, int out_size, void* d_ws, size_t ws_size,
                              hipStream_t stream)
{
    const int*   spk = (const int*)d_in[1];
    const float* te  = (const float*)d_in[2];
    const float* edu = (const float*)d_in[3];
    const float* Wk  = (const float*)d_in[4];
    const float* Wv  = (const float*)d_in[5];
    const float* Wq  = (const float*)d_in[6];
    float* out = (float*)d_out;

    // ws layout (ush units), ~29 MB total:
    unsigned short* bf    = (unsigned short*)d_ws;
    unsigned short* wq_bb = bf;                 //   589824
    unsigned short* edu_b = bf + 589824u;       //   196608
    unsigned short* wk_bb = bf + 786432u;       //   589824
    unsigned short* wv_bb = bf + 1376256u;      //   589824
    unsigned short* Mtbuf = bf + 1966080u;      // 12582912

    conv_bf16<<<960,             256, 0, stream>>>(Wq, edu, Wk, Wv, bf);
    kvm      <<<dim3(NH, NB, 2), 256, 0, stream>>>(edu_b, wk_bb, wv_bb, spk, Mtbuf);
    fused_qm <<<6 * NT * NB,     256, 0, stream>>>(te, wq_bb, Mtbuf, out);
}